// Round 12
// baseline (311.514 us; speedup 1.0000x reference)
//
#include <hip/hip_runtime.h>
#include <hip/hip_bf16.h>
#include <math.h>

// Problem constants
#define B 4
#define N 1024
#define C 768
#define H 8
#define D 96

typedef _Float16 half8 __attribute__((ext_vector_type(8)));
typedef _Float16 half4 __attribute__((ext_vector_type(4)));
typedef _Float16 h2 __attribute__((ext_vector_type(2)));
typedef float f32x4 __attribute__((ext_vector_type(4)));

#define BN_RSQ 0.9999950000374997f    // 1/sqrt(1+1e-5)
#define QK_SCALE 0.10206207261596577f // 96^-0.5

static __device__ __forceinline__ h2 u32_to_h2(unsigned int u) {
    union { unsigned int u; h2 h; } c; c.u = u; return c.h;
}

// ---------------------------------------------------------------------------
// K0: pre-splat w2[g,h] = gamma[g]*BN_RSQ*rw[g,h] into half2 (both lanes eq).
// ---------------------------------------------------------------------------
__global__ __launch_bounds__(64) void w2prep(const float* __restrict__ rw,
                                             const float* __restrict__ gamma,
                                             unsigned int* __restrict__ w2pk) {
    int t = threadIdx.x;            // 0..63
    int g = t >> 3, h = t & 7;
    float w = gamma[g] * BN_RSQ * rw[g * 8 + h];
    union { _Float16 f; unsigned short s; } c; c.f = (_Float16)w;
    w2pk[t] = (unsigned int)c.s | ((unsigned int)c.s << 16);
}

// ---------------------------------------------------------------------------
// K1: per-token 3x3 conv for q/k/v in one launch (blockIdx.y selects tensor).
// ---------------------------------------------------------------------------
__global__ __launch_bounds__(256) void conv_all(const float* __restrict__ q,
                                                const float* __restrict__ k,
                                                const float* __restrict__ v,
                                                const float* __restrict__ qw,
                                                const float* __restrict__ kw,
                                                const float* __restrict__ vw,
                                                _Float16* __restrict__ qo,
                                                _Float16* __restrict__ ko,
                                                _Float16* __restrict__ vo) {
    const int sel = blockIdx.y;
    const float* x = sel == 0 ? q : sel == 1 ? k : v;
    const float* w = sel == 0 ? qw : sel == 1 ? kw : vw;
    _Float16* out = sel == 0 ? qo : sel == 1 ? ko : vo;
    __shared__ float sx[768];
    __shared__ float sw[81];
    int t = blockIdx.x;
    const float* xt = x + (size_t)t * 768;
    int tid = threadIdx.x;
    sx[tid]       = xt[tid];
    sx[tid + 256] = xt[tid + 256];
    sx[tid + 512] = xt[tid + 512];
    if (tid < 81) sw[tid] = w[tid];
    __syncthreads();
    int i = tid >> 4, j = tid & 15;
    float acc0 = 0.f, acc1 = 0.f, acc2 = 0.f;
    #pragma unroll
    for (int c = 0; c < 3; ++c) {
        #pragma unroll
        for (int di = 0; di < 3; ++di) {
            int ii = i + di - 1;
            if (ii < 0 || ii > 15) continue;
            #pragma unroll
            for (int dj = 0; dj < 3; ++dj) {
                int jj = j + dj - 1;
                if (jj < 0 || jj > 15) continue;
                float xv = sx[c * 256 + ii * 16 + jj];
                acc0 += xv * sw[(0 * 3 + c) * 9 + di * 3 + dj];
                acc1 += xv * sw[(1 * 3 + c) * 9 + di * 3 + dj];
                acc2 += xv * sw[(2 * 3 + c) * 9 + di * 3 + dj];
            }
        }
    }
    _Float16* ot = out + (size_t)t * 768;
    ot[0 * 256 + tid] = (_Float16)acc0;
    ot[1 * 256 + tid] = (_Float16)acc1;
    ot[2 * 256 + tid] = (_Float16)acc2;
}

// ---------------------------------------------------------------------------
// K2: transpose V: vcT[b*768 + c][m] = vcH[b*N + m][c]   (f16)
// ---------------------------------------------------------------------------
__global__ __launch_bounds__(256) void transpose_v(const _Float16* __restrict__ vcH,
                                                   _Float16* __restrict__ vcT) {
    __shared__ _Float16 tile[64][66];
    int n0 = blockIdx.x * 64, c0 = blockIdx.y * 64, b = blockIdx.z;
    int tid = threadIdx.x;
    for (int i = tid; i < 4096; i += 256) {
        int r = i >> 6, c = i & 63;
        tile[r][c] = vcH[((size_t)(b * N + n0 + r)) * C + c0 + c];
    }
    __syncthreads();
    for (int i = tid; i < 4096; i += 256) {
        int cr = i >> 6, nc = i & 63;
        vcT[((size_t)(b * 768 + c0 + cr)) * N + n0 + nc] = tile[nc][cr];
    }
}

// ---------------------------------------------------------------------------
// K3: vsum[row] = sum_m vcT[row][m], row = b*768+c. One wave per row.
// ---------------------------------------------------------------------------
__global__ __launch_bounds__(256) void vsum_row(const _Float16* __restrict__ vcT,
                                                float* __restrict__ vsum) {
    int row = blockIdx.x * 4 + (threadIdx.x >> 6);
    int lane = threadIdx.x & 63;
    const _Float16* p = vcT + (size_t)row * N;
    float s = 0.f;
    #pragma unroll
    for (int it = 0; it < 2; ++it) {
        half8 v = *(const half8*)(p + (it * 64 + lane) * 8);
        #pragma unroll
        for (int i = 0; i < 8; ++i) s += (float)v[i];
    }
    #pragma unroll
    for (int off = 1; off < 64; off <<= 1) s += __shfl_xor(s, off);
    if (lane == 0) vsum[row] = s;
}

// ---------------------------------------------------------------------------
// K4: QK^T with f16 MFMA (R7-verified verbatim). Writes expS (f16) via LDS
// staging (coalesced half8 rows) and atomicAdds row sums into Lrow.
// grid (8,8,32): 128x128 tile per (b,h). block 256 (4 waves, 2x2).
// ---------------------------------------------------------------------------
__global__ __launch_bounds__(256) void qk_mfma(const _Float16* __restrict__ qcH,
                                               const _Float16* __restrict__ kcH,
                                               _Float16* __restrict__ expS,
                                               float* __restrict__ Lrow) {
    __shared__ __align__(16) char smem[49152];   // Q(24K) | K(24K); reused: P staging 128x136 f16
    char* Qb = smem;
    char* Kb = smem + 24576;
    const int n0 = blockIdx.x * 128, m0 = blockIdx.y * 128, z = blockIdx.z;
    const int b = z >> 3, h = z & 7;
    const int tid = threadIdx.x;
    const _Float16* qg = qcH + ((size_t)(b * N + n0)) * C + h * D;
    const _Float16* kg = kcH + ((size_t)(b * N + m0)) * C + h * D;
    #pragma unroll
    for (int it = 0; it < 6; ++it) {
        int chunk = it * 256 + tid;          // 0..1535
        int r = chunk / 12, cc = (chunk - r * 12) * 8;
        half8 qv = *(const half8*)(qg + (size_t)r * C + cc);
        half8 kv = *(const half8*)(kg + (size_t)r * C + cc);
        int off = ((r * 96 + cc) * 2) ^ ((r & 7) << 4);
        *(half8*)(Qb + off) = qv;
        *(half8*)(Kb + off) = kv;
    }
    __syncthreads();
    const int wid = tid >> 6, lane = tid & 63;
    const int wr = wid >> 1, wc = wid & 1;
    const int l15 = lane & 15, l4 = lane >> 4;
    f32x4 acc[4][4] = {};
    #pragma unroll
    for (int ks = 0; ks < 3; ++ks) {
        int k0 = ks * 32 + l4 * 8;
        half8 a[4], bf[4];
        #pragma unroll
        for (int fm = 0; fm < 4; ++fm) {
            int row = wr * 64 + fm * 16 + l15;
            a[fm] = *(half8*)(Qb + (((row * 96 + k0) * 2) ^ ((row & 7) << 4)));
        }
        #pragma unroll
        for (int fn = 0; fn < 4; ++fn) {
            int row = wc * 64 + fn * 16 + l15;
            bf[fn] = *(half8*)(Kb + (((row * 96 + k0) * 2) ^ ((row & 7) << 4)));
        }
        #pragma unroll
        for (int fm = 0; fm < 4; ++fm)
            #pragma unroll
            for (int fn = 0; fn < 4; ++fn)
                acc[fm][fn] = __builtin_amdgcn_mfma_f32_16x16x32_f16(a[fm], bf[fn], acc[fm][fn], 0, 0, 0);
    }
    __syncthreads();   // all waves done reading Qb/Kb; smem reused for P staging
    // exp -> LDS staging (rows padded to 136), row sums -> atomicAdd Lrow
    #pragma unroll
    for (int fm = 0; fm < 4; ++fm) {
        #pragma unroll
        for (int j = 0; j < 4; ++j) {
            int row = wr * 64 + fm * 16 + l4 * 4 + j;
            float rs = 0.f;
            #pragma unroll
            for (int fn = 0; fn < 4; ++fn) {
                float p = __expf(acc[fm][fn][j] * QK_SCALE);
                rs += p;
                int col = wc * 64 + fn * 16 + l15;
                *(_Float16*)(smem + (row * 136 + col) * 2) = (_Float16)p;
            }
            rs += __shfl_xor(rs, 1);
            rs += __shfl_xor(rs, 2);
            rs += __shfl_xor(rs, 4);
            rs += __shfl_xor(rs, 8);
            if (l15 == 0) atomicAdd(&Lrow[z * N + n0 + row], rs);
        }
    }
    __syncthreads();
    // coalesced store: half8 per thread, 256B contiguous per 16-thread group
    _Float16* eg = expS + ((size_t)z * N + n0) * N + m0;
    #pragma unroll
    for (int it = 0; it < 8; ++it) {
        int q2 = it * 256 + tid;             // 0..2047
        int row = q2 >> 4, col8 = (q2 & 15) * 8;
        half8 v = *(half8*)(smem + (row * 136 + col8) * 2);
        *(half8*)(eg + (size_t)row * N + col8) = v;
    }
}

// ---------------------------------------------------------------------------
// K5: pv3 — barrier-free, LDS-free normalize + head-mix + PV.
// Each lane builds its PV A-fragment A'[g][n=l15][m=l4*8..+7] IN REGISTERS:
//   A' = sum_h w2[g,h] * (expS[h][n][m] * IL[h,n])   (packed f16 math)
// Wave w handles g in {2w, 2w+1} (each expS load feeds 2 groups).
// grid 1024 = B x 64 n16-tiles x 4 m-quarters, XCD-pinned by (b,mq).
// block 256 (4 waves). x accumulated via atomicAdd (4 writers per element).
// ---------------------------------------------------------------------------
__global__ __launch_bounds__(256) void pv3(const _Float16* __restrict__ expS,
                                           const float* __restrict__ Lrow,
                                           const _Float16* __restrict__ vcT,
                                           const unsigned int* __restrict__ w2pk,
                                           float* __restrict__ x) {
    const int gid = blockIdx.x;              // 0..1023
    const int xcd = gid & 7;
    const int idx = gid >> 3;                // 0..127
    const int bmq = xcd * 2 + (idx & 1);     // 0..15 -> (b, m-quarter) per XCD
    const int b = bmq >> 2, mq = bmq & 3;
    const int n0 = (idx >> 1) * 16;          // 0..1008
    const int mbase = mq * 256;
    const int tid = threadIdx.x;
    const int wv = tid >> 6, lane = tid & 63;
    const int l15 = lane & 15, l4 = lane >> 4;
    const int g0 = wv * 2;
    // per-lane 1/L for row n0+l15, all 8 heads (splatted h2)
    h2 IL2[8];
    #pragma unroll
    for (int h = 0; h < 8; ++h) {
        float il = 1.0f / Lrow[(size_t)(b * 8 + h) * N + n0 + l15];
        _Float16 i16 = (_Float16)il;
        h2 t; t[0] = i16; t[1] = i16;
        IL2[h] = t;
    }
    f32x4 acc[2][6] = {};
    const size_t erow = ((size_t)(b * 8) * N + n0 + l15) * N;  // h=0 row base
    const size_t estride = (size_t)N * N;                       // per-h stride
    #pragma unroll
    for (int mt = 0; mt < 4; ++mt) {
        const int m0 = mbase + mt * 64;
        #pragma unroll
        for (int ks2 = 0; ks2 < 2; ++ks2) {
            const int moff = m0 + ks2 * 32 + l4 * 8;
            // load 8 heads' expS half8 and normalize (packed)
            h2 pn[8][4];
            #pragma unroll
            for (int h = 0; h < 8; ++h) {
                half8 p8 = *(const half8*)(expS + erow + (size_t)h * estride + moff);
                #pragma unroll
                for (int i = 0; i < 4; ++i) {
                    h2 t; t[0] = p8[2 * i]; t[1] = p8[2 * i + 1];
                    pn[h][i] = t * IL2[h];
                }
            }
            // mix into 2 groups and run PV MFMA
            #pragma unroll
            for (int gg = 0; gg < 2; ++gg) {
                const int g = g0 + gg;
                h2 am[4] = {};
                #pragma unroll
                for (int h = 0; h < 8; ++h) {
                    h2 w = u32_to_h2(w2pk[g * 8 + h]);   // uniform -> SGPR
                    #pragma unroll
                    for (int i = 0; i < 4; ++i) am[i] = w * pn[h][i] + am[i];
                }
                half8 af;
                #pragma unroll
                for (int i = 0; i < 4; ++i) { af[2 * i] = am[i][0]; af[2 * i + 1] = am[i][1]; }
                #pragma unroll
                for (int fn2 = 0; fn2 < 6; ++fn2) {
                    half8 vf = *(const half8*)(vcT + (size_t)(b * 768 + g * 96 + fn2 * 16 + l15) * N + moff);
                    acc[gg][fn2] = __builtin_amdgcn_mfma_f32_16x16x32_f16(af, vf, acc[gg][fn2], 0, 0, 0);
                }
            }
        }
    }
    #pragma unroll
    for (int gg = 0; gg < 2; ++gg)
        #pragma unroll
        for (int fn2 = 0; fn2 < 6; ++fn2)
            #pragma unroll
            for (int j = 0; j < 4; ++j) {
                int n = n0 + l4 * 4 + j;
                int c = (g0 + gg) * 96 + fn2 * 16 + l15;
                atomicAdd(&x[((size_t)(b * N + n)) * C + c], acc[gg][fn2][j]);
            }
}

// ---------------------------------------------------------------------------
// K6: projection out = (x + cg*vsum) @ pw^T + pb  with f16 MFMA.
// grid (32 t-tiles x128, 8 c'-tiles x96). block 256 (4 waves, 2x2).
// ---------------------------------------------------------------------------
__global__ __launch_bounds__(256) void proj_mfma(const float* __restrict__ x,
                                                 const float* __restrict__ vsum,
                                                 const float* __restrict__ pw,
                                                 const float* __restrict__ pb,
                                                 const float* __restrict__ rb,
                                                 const float* __restrict__ gamma,
                                                 const float* __restrict__ beta,
                                                 float* __restrict__ out) {
    __shared__ _Float16 sX[128 * 32];
    __shared__ _Float16 sW[96 * 32];
    const int t0 = blockIdx.x * 128, c0 = blockIdx.y * 96;
    const int b = t0 >> 10;
    const int tid = threadIdx.x;
    const int wid = tid >> 6, lane = tid & 63;
    const int wr = wid >> 1, wc = wid & 1;
    const int l15 = lane & 15, l4 = lane >> 4;
    char* Xb = (char*)sX;
    char* Wb = (char*)sW;
    f32x4 acc[4][3] = {};
    for (int k0 = 0; k0 < 768; k0 += 32) {
        __syncthreads();   // prev MFMA done
        #pragma unroll
        for (int it = 0; it < 4; ++it) {
            int q = it * 256 + tid;            // 0..1023
            int r = q >> 3, c4 = (q & 7) * 4;
            f32x4 xv = *(const f32x4*)(x + (size_t)(t0 + r) * C + k0 + c4);
            int g = (k0 + c4) / 96;
            float cg = gamma[g] * BN_RSQ * rb[g] + beta[g];
            const f32x4 vs = *(const f32x4*)(vsum + b * 768 + k0 + c4);
            half4 hv;
            #pragma unroll
            for (int i = 0; i < 4; ++i) hv[i] = (_Float16)(xv[i] + cg * vs[i]);
            *(half4*)(Xb + (((r * 32 + c4) * 2) ^ ((r & 7) << 4))) = hv;
        }
        #pragma unroll
        for (int it = 0; it < 3; ++it) {
            int q = it * 256 + tid;            // 0..767
            int r = q >> 3, c4 = (q & 7) * 4;
            f32x4 wv = *(const f32x4*)(pw + (size_t)(c0 + r) * C + k0 + c4);
            half4 hv;
            #pragma unroll
            for (int i = 0; i < 4; ++i) hv[i] = (_Float16)wv[i];
            *(half4*)(Wb + (((r * 32 + c4) * 2) ^ ((r & 7) << 4))) = hv;
        }
        __syncthreads();
        half8 af[4];
        #pragma unroll
        for (int fm = 0; fm < 4; ++fm) {
            int r = wr * 64 + fm * 16 + l15;
            af[fm] = *(half8*)(Xb + (((r * 32 + l4 * 8) * 2) ^ ((r & 7) << 4)));
        }
        #pragma unroll
        for (int fn = 0; fn < 3; ++fn) {
            int r = wc * 48 + fn * 16 + l15;
            half8 bf = *(half8*)(Wb + (((r * 32 + l4 * 8) * 2) ^ ((r & 7) << 4)));
            #pragma unroll
            for (int fm = 0; fm < 4; ++fm)
                acc[fm][fn] = __builtin_amdgcn_mfma_f32_16x16x32_f16(af[fm], bf, acc[fm][fn], 0, 0, 0);
        }
    }
    #pragma unroll
    for (int fm = 0; fm < 4; ++fm)
        #pragma unroll
        for (int fn = 0; fn < 3; ++fn) {
            int cc = c0 + wc * 48 + fn * 16 + l15;
            float bias = pb[cc];
            #pragma unroll
            for (int j = 0; j < 4; ++j) {
                int t = t0 + wr * 64 + fm * 16 + l4 * 4 + j;
                out[(size_t)t * C + cc] = acc[fm][fn][j] + bias;
            }
        }
}

// ---------------------------------------------------------------------------
extern "C" void kernel_launch(void* const* d_in, const int* in_sizes, int n_in,
                              void* d_out, int out_size, void* d_ws, size_t ws_size,
                              hipStream_t stream) {
    const float* q     = (const float*)d_in[0];
    const float* k     = (const float*)d_in[1];
    const float* v     = (const float*)d_in[2];
    const float* qw    = (const float*)d_in[3];
    const float* kw    = (const float*)d_in[4];
    const float* vw    = (const float*)d_in[5];
    const float* rw    = (const float*)d_in[6];
    const float* rb    = (const float*)d_in[7];
    const float* gamma = (const float*)d_in[8];
    const float* beta  = (const float*)d_in[9];
    const float* pw    = (const float*)d_in[10];
    const float* pb    = (const float*)d_in[11];
    float* out = (float*)d_out;

    // Workspace layout (bytes, 256-aligned):
    char* ws = (char*)d_ws;
    _Float16* expS = (_Float16*)ws;                       // 67,108,864 B
    float*    xacc = (float*)(ws + 67108864);             // 12,582,912 B
    _Float16* qcH  = (_Float16*)(ws + 79691776);          //  6,291,456 B
    _Float16* kcH  = (_Float16*)(ws + 85983232);
    _Float16* vcH  = (_Float16*)(ws + 92274688);
    _Float16* vcT  = (_Float16*)(ws + 98566144);
    float*    Lrow = (float*)(ws + 104857600);            //    131,072 B
    float*    vsum = (float*)(ws + 104988672);            //     12,288 B
    unsigned int* w2pk = (unsigned int*)(ws + 105000960); //        256 B
    // total ~105 MB

    hipMemsetAsync(Lrow, 0, 131072, stream);
    hipMemsetAsync(xacc, 0, 12582912, stream);

    w2prep<<<dim3(1), dim3(64), 0, stream>>>(rw, gamma, w2pk);

    conv_all<<<dim3(B * N, 3), dim3(256), 0, stream>>>(q, k, v, qw, kw, vw, qcH, kcH, vcH);

    transpose_v<<<dim3(16, 12, B), dim3(256), 0, stream>>>(vcH, vcT);
    vsum_row<<<dim3(768), dim3(256), 0, stream>>>(vcT, vsum);

    qk_mfma<<<dim3(8, 8, 8 * B), dim3(256), 0, stream>>>(qcH, kcH, expS, Lrow);

    pv3<<<dim3(1024), dim3(256), 0, stream>>>(expS, Lrow, vcT, w2pk, xacc);

    proj_mfma<<<dim3(32, 8), dim3(256), 0, stream>>>(xacc, vsum, pw, pb, rb, gamma, beta, out);
}